// Round 11
// baseline (147.564 us; speedup 1.0000x reference)
//
#include <hip/hip_runtime.h>
#include <hip/hip_bf16.h>

typedef __attribute__((ext_vector_type(8))) short s8v;
typedef __attribute__((ext_vector_type(4))) short s4v;
typedef __attribute__((ext_vector_type(4))) float f32x4;

#define MFMA_BF16 __builtin_amdgcn_mfma_f32_16x16x32_bf16

__device__ inline void gload_lds16(const __hip_bfloat16* g, __hip_bfloat16* l) {
  __builtin_amdgcn_global_load_lds(
      (const __attribute__((address_space(1))) void*)g,
      (__attribute__((address_space(3))) void*)l, 16, 0, 0);
}

__device__ inline short f2bs(float x) {
  __hip_bfloat16 b = __float2bfloat16(x);
  return *reinterpret_cast<short*>(&b);
}

// ---- prep: (z<16) X[n][c][p] fp32 -> XT[n][p][c] bf16 + Xc[n][c][p] bf16
//      (z==16) weight casts
__global__ __launch_bounds__(256) void prep(const float* __restrict__ X,
                                            __hip_bfloat16* __restrict__ XT,
                                            __hip_bfloat16* __restrict__ Xc,
                                            const float* __restrict__ Wq,
                                            const float* __restrict__ Wv,
                                            const float* __restrict__ Wk,
                                            const float* __restrict__ Wo,
                                            const float* __restrict__ bq,
                                            const float* __restrict__ bv,
                                            __hip_bfloat16* __restrict__ WA,
                                            __hip_bfloat16* __restrict__ WkT,
                                            __hip_bfloat16* __restrict__ WOb,
                                            float* __restrict__ biasKV) {
  const int tid = threadIdx.x;
  if (blockIdx.z == 16) {  // weight casts: 128 blocks x 8 iters x 256 threads
    const int blk = blockIdx.y * 16 + blockIdx.x;
#pragma unroll
    for (int t = 0; t < 8; ++t) {
      const int i = (blk * 8 + t) * 256 + tid;  // < 262144
      WA[i] = __float2bfloat16(Wq[i]);
      WA[262144 + i] = __float2bfloat16(Wv[i]);
      WOb[i] = __float2bfloat16(Wo[i]);
      WkT[i] = __float2bfloat16(Wk[(i & 511) * 512 + (i >> 9)]);
      if (i < 512) { biasKV[i] = bq[i]; biasKV[512 + i] = bv[i]; }
    }
    return;
  }
  __shared__ float tl[64][65];
  const int n = blockIdx.z;
  const int c0 = blockIdx.y * 64, p0 = blockIdx.x * 64;
  const int lr = tid >> 4, lc4 = (tid & 15) * 4;
  const float* Xp = X + ((long)n * 512 + c0) * 1024 + p0;
  __hip_bfloat16* Xcp = Xc + ((long)n * 512 + c0) * 1024 + p0;
#pragma unroll
  for (int i = 0; i < 4; ++i) {
    const int ch = i * 16 + lr;
    const float4 v = *(const float4*)&Xp[(long)ch * 1024 + lc4];
    tl[ch][lc4 + 0] = v.x; tl[ch][lc4 + 1] = v.y;
    tl[ch][lc4 + 2] = v.z; tl[ch][lc4 + 3] = v.w;
    s4v xo;
    xo[0] = f2bs(v.x); xo[1] = f2bs(v.y); xo[2] = f2bs(v.z); xo[3] = f2bs(v.w);
    *(s4v*)&Xcp[(long)ch * 1024 + lc4] = xo;  // straight bf16 copy for residual
  }
  __syncthreads();
  __hip_bfloat16* XTp = XT + ((long)n * 1024 + p0) * 512 + c0;
#pragma unroll
  for (int i = 0; i < 4; ++i) {
    const int px = i * 16 + lr;
    s4v o;
#pragma unroll
    for (int e = 0; e < 4; ++e) o[e] = f2bs(tl[lc4 + e][px]);
    *(s4v*)&XTp[(long)px * 512 + lc4] = o;
  }
}

// ---- kvm: K_h,V_h tiles computed on the fly (never hit HBM) + M-partial ---
// block b=(n,h,t): phase1 dual-A GEMM (K=Wq_h*XTt^T, V=Wv_h*XTt^T, 64x128
// each, shared B-tile); phase2 +bias -> bf16 KS/VS [64][136] LDS; phase3
// M-part = V*K^T over 128 px -> fp32 Part[b][64][64] (transposed [j][i]).
// part2 (32 KiB) overlays the dead phase-1 staging region.
__global__ __launch_bounds__(256) void kvm(const __hip_bfloat16* __restrict__ WA,
                                           const __hip_bfloat16* __restrict__ XT,
                                           const float* __restrict__ bKV,
                                           float* __restrict__ Part) {
  const int b = blockIdx.x;  // 1024: n=b>>6, h=(b>>3)&7, t=b&7
  const int n = b >> 6, h = (b >> 3) & 7, t = b & 7;
  const int tid = threadIdx.x, wid = tid >> 6, lane = tid & 63;
  const int wm = wid >> 1, wn = wid & 1;
  const int cr = (lane >> 4) * 4, cc = lane & 15;

  __shared__ __hip_bfloat16 KS[64 * 136];   // 17 KiB, +8 pad
  __shared__ __hip_bfloat16 VS[64 * 136];   // 17 KiB
  __shared__ float part2[2][4096];          // 32 KiB, overlays staging
  __hip_bfloat16* AqS = (__hip_bfloat16*)&part2[0][0];  //  8 KiB [64][64]
  __hip_bfloat16* AvS = AqS + 64 * 64;                  //  8 KiB
  __hip_bfloat16* BS  = AvS + 64 * 64;                  // 16 KiB [128][64]

  f32x4 aK[2][4] = {}, aV[2][4] = {};

  const int r8 = lane >> 3, b8 = (lane & 7) * 8;
  const __hip_bfloat16* gq = WA + (long)(h * 64 + wid * 16 + r8) * 512 + b8;
  const __hip_bfloat16* gv = gq + (long)512 * 512;
  const __hip_bfloat16* gx = XT + (long)(n * 1024 + t * 128 + wid * 32 + r8) * 512 + b8;

  for (int k0 = 0; k0 < 512; k0 += 64) {
#pragma unroll
    for (int u = 0; u < 2; ++u) {
      gload_lds16(gq + (long)(u * 8) * 512 + k0, &AqS[(wid * 16 + u * 8) * 64]);
      gload_lds16(gv + (long)(u * 8) * 512 + k0, &AvS[(wid * 16 + u * 8) * 64]);
    }
#pragma unroll
    for (int u = 0; u < 4; ++u)
      gload_lds16(gx + (long)(u * 8) * 512 + k0, &BS[(wid * 32 + u * 8) * 64]);
    __syncthreads();
#pragma unroll
    for (int ks = 0; ks < 2; ++ks) {
      const int ko = ks * 32 + (lane >> 4) * 8;
      s8v q[2], v[2], bb[4];
#pragma unroll
      for (int i = 0; i < 2; ++i) {
        q[i] = *(const s8v*)&AqS[(wm * 32 + i * 16 + cc) * 64 + ko];
        v[i] = *(const s8v*)&AvS[(wm * 32 + i * 16 + cc) * 64 + ko];
      }
#pragma unroll
      for (int j = 0; j < 4; ++j)
        bb[j] = *(const s8v*)&BS[(wn * 64 + j * 16 + cc) * 64 + ko];
#pragma unroll
      for (int i = 0; i < 2; ++i)
#pragma unroll
        for (int j = 0; j < 4; ++j) {
          aK[i][j] = MFMA_BF16(q[i], bb[j], aK[i][j], 0, 0, 0);
          aV[i][j] = MFMA_BF16(v[i], bb[j], aV[i][j], 0, 0, 0);
        }
    }
    __syncthreads();
  }

  // phase 2: +bias, bf16 -> KS/VS [ch][px]
#pragma unroll
  for (int i = 0; i < 2; ++i)
#pragma unroll
    for (int r = 0; r < 4; ++r) {
      const int ch = wm * 32 + i * 16 + cr + r;
      const float bk_ = bKV[h * 64 + ch];
      const float bv_ = bKV[512 + h * 64 + ch];
#pragma unroll
      for (int j = 0; j < 4; ++j) {
        const int px = wn * 64 + j * 16 + cc;
        KS[ch * 136 + px] = __float2bfloat16(aK[i][j][r] + bk_);
        VS[ch * 136 + px] = __float2bfloat16(aV[i][j][r] + bv_);
      }
    }
  __syncthreads();

  // phase 3: M-partial = V*K^T over 128 px; wave wid owns px [wid*32,+32)
  f32x4 m[4][4] = {};
  {
    const int pxb = wid * 32 + (lane >> 4) * 8;
    s8v av[4], ak[4];
#pragma unroll
    for (int i = 0; i < 4; ++i)
      av[i] = *(const s8v*)&VS[((lane & 15) + i * 16) * 136 + pxb];
#pragma unroll
    for (int j = 0; j < 4; ++j)
      ak[j] = *(const s8v*)&KS[((lane & 15) + j * 16) * 136 + pxb];
#pragma unroll
    for (int i = 0; i < 4; ++i)
#pragma unroll
      for (int j = 0; j < 4; ++j)
        m[i][j] = MFMA_BF16(av[i], ak[j], m[i][j], 0, 0, 0);
  }
  // 2-stage wave reduction into part2 (staging region is dead)
  if (wid < 2) {
#pragma unroll
    for (int i = 0; i < 4; ++i)
#pragma unroll
      for (int r = 0; r < 4; ++r)
#pragma unroll
        for (int j = 0; j < 4; ++j)
          part2[wid][(i * 16 + cr + r) * 64 + j * 16 + cc] = m[i][j][r];
  }
  __syncthreads();
  if (wid >= 2) {
#pragma unroll
    for (int i = 0; i < 4; ++i)
#pragma unroll
      for (int r = 0; r < 4; ++r)
#pragma unroll
        for (int j = 0; j < 4; ++j)
          part2[wid - 2][(i * 16 + cr + r) * 64 + j * 16 + cc] += m[i][j][r];
  }
  __syncthreads();
  float* outp = Part + (long)b * 4096;
  for (int e = tid; e < 4096; e += 256)
    outp[(e & 63) * 64 + (e >> 6)] = part2[0][e] + part2[1][e];  // [j][i]
}

// ---- wchain: W''[n] = (Wo * blockdiag(M[n])) * Wk,  b2[n] = W'*bk + bo ----
// Mt_h staged by summing the 8 fp32 kvm partials (fp32 add, then bf16).
__global__ __launch_bounds__(256) void wchain(const __hip_bfloat16* __restrict__ WOb,
                                              const __hip_bfloat16* __restrict__ WkT,
                                              const float* __restrict__ Part,
                                              const float* __restrict__ bk,
                                              const float* __restrict__ bo,
                                              __hip_bfloat16* __restrict__ WPP,
                                              float* __restrict__ b2out) {
  const int c0 = blockIdx.x * 128, o0 = blockIdx.y * 128, n = blockIdx.z;
  const int tid = threadIdx.x, wid = tid >> 6, lane = tid & 63;
  const int wm = wid >> 1, wn = wid & 1;
  const int cr = (lane >> 4) * 4, cc = lane & 15;

  __shared__ __hip_bfloat16 WoS[128 * 64];
  __shared__ __hip_bfloat16 WkS[128 * 64];
  __shared__ __hip_bfloat16 MtS[64 * 64];
  __shared__ __hip_bfloat16 W1S[128 * 64];
  __shared__ float bkS[512];

  if (tid < 128) *(float4*)&bkS[tid * 4] = *(const float4*)&bk[tid * 4];

  f32x4 acc2[4][4] = {};
  float bacc = 0.f;
  const int r8 = lane >> 3, b8 = (lane & 7) * 8;

  for (int h = 0; h < 8; ++h) {
#pragma unroll
    for (int t = 0; t < 4; ++t) {
      const int row = wid * 32 + t * 8;
      gload_lds16(WOb + (long)(o0 + row + r8) * 512 + h * 64 + b8, &WoS[row * 64]);
      gload_lds16(WkT + (long)(c0 + row + r8) * 512 + h * 64 + b8, &WkS[row * 64]);
    }
    {  // Mt_h = sum of 8 fp32 partials -> bf16
      const float* P0 = Part + ((long)((n * 8 + h) * 8)) * 4096;
#pragma unroll
      for (int q = 0; q < 4; ++q) {
        const int e = tid * 16 + q * 4;
        float4 s = *(const float4*)&P0[e];
#pragma unroll
        for (int p = 1; p < 8; ++p) {
          const float4 x = *(const float4*)&P0[(long)p * 4096 + e];
          s.x += x.x; s.y += x.y; s.z += x.z; s.w += x.w;
        }
        s4v o;
        o[0] = f2bs(s.x); o[1] = f2bs(s.y); o[2] = f2bs(s.z); o[3] = f2bs(s.w);
        *(s4v*)&MtS[e] = o;
      }
    }
    __syncthreads();

    f32x4 acc1[2][4] = {};
#pragma unroll
    for (int ks = 0; ks < 2; ++ks) {
      const int ko = ks * 32 + (lane >> 4) * 8;
      s8v aj[2], bw[4];
#pragma unroll
      for (int i = 0; i < 2; ++i)
        aj[i] = *(const s8v*)&MtS[(wn * 32 + i * 16 + cc) * 64 + ko];
#pragma unroll
      for (int t = 0; t < 4; ++t)
        bw[t] = *(const s8v*)&WoS[(wm * 64 + t * 16 + cc) * 64 + ko];
#pragma unroll
      for (int i = 0; i < 2; ++i)
#pragma unroll
        for (int t = 0; t < 4; ++t)
          acc1[i][t] = MFMA_BF16(aj[i], bw[t], acc1[i][t], 0, 0, 0);
    }
#pragma unroll
    for (int i = 0; i < 2; ++i)
#pragma unroll
      for (int t = 0; t < 4; ++t) {
        const int o = wm * 64 + t * 16 + cc;
        const int jb = wn * 32 + i * 16 + cr;
        s4v p;
#pragma unroll
        for (int r = 0; r < 4; ++r) p[r] = f2bs(acc1[i][t][r]);
        *(s4v*)((char*)W1S + ((o * 128 + jb * 2) ^ ((o & 7) << 4))) = p;
      }
    __syncthreads();

#pragma unroll
    for (int ks = 0; ks < 2; ++ks) {
      const int ko = ks * 32 + (lane >> 4) * 8;
      s8v a2[4], bw[4];
#pragma unroll
      for (int i = 0; i < 4; ++i) {
        const int o = wm * 64 + i * 16 + cc;
        a2[i] = *(const s8v*)((char*)W1S + ((o * 128 + ko * 2) ^ ((o & 7) << 4)));
      }
#pragma unroll
      for (int t = 0; t < 4; ++t)
        bw[t] = *(const s8v*)&WkS[(wn * 64 + t * 16 + cc) * 64 + ko];
#pragma unroll
      for (int i = 0; i < 4; ++i)
#pragma unroll
        for (int t = 0; t < 4; ++t)
          acc2[i][t] = MFMA_BF16(a2[i], bw[t], acc2[i][t], 0, 0, 0);
    }

    if (c0 == 0) {
      const int o = tid >> 1, half = tid & 1;
      float s = 0.f;
#pragma unroll
      for (int q = 0; q < 4; ++q) {
        const int jb = half * 64 + q * 16;
        const s8v w = *(const s8v*)((char*)W1S + ((o * 128 + jb) ^ ((o & 7) << 4)));
        const __hip_bfloat16* wb = (const __hip_bfloat16*)&w;
#pragma unroll
        for (int e = 0; e < 8; ++e)
          s += __bfloat162float(wb[e]) * bkS[h * 64 + half * 32 + q * 8 + e];
      }
      bacc += s;
    }
    __syncthreads();
  }

#pragma unroll
  for (int i = 0; i < 4; ++i)
#pragma unroll
    for (int r = 0; r < 4; ++r)
#pragma unroll
      for (int t = 0; t < 4; ++t)
        WPP[((long)n * 512 + o0 + wm * 64 + i * 16 + cr + r) * 512 +
            c0 + wn * 64 + t * 16 + cc] = __float2bfloat16(acc2[i][t][r]);
  if (c0 == 0) {
    const float tot = bacc + __shfl_xor(bacc, 1);
    if ((tid & 1) == 0) {
      const int o = tid >> 1;
      b2out[n * 512 + o0 + o] = tot + bo[o0 + o];
    }
  }
}

// ---- ygn v2: fused Y-GEMM + GroupNorm + residual, conflict-free ----------
__global__ __launch_bounds__(512) void ygn(const __hip_bfloat16* __restrict__ WPP,
                                           const __hip_bfloat16* __restrict__ XT,
                                           const float* __restrict__ b2,
                                           const __hip_bfloat16* __restrict__ Xc,
                                           const float* __restrict__ gw,
                                           const float* __restrict__ gb,
                                           float* __restrict__ out) {
  const int id = blockIdx.x;            // 256 blocks
  const int xcd = id & 7, slot = id >> 3;
  const int n = xcd * 2 + (slot >> 4);  // 2 n per XCD -> XT[n] L2-resident
  const int ch0 = (slot & 15) * 32;
  const int tid = threadIdx.x, wid = tid >> 6, lane = tid & 63;
  const int wm = wid & 1, wpx = wid >> 1;
  const int cc = lane & 15, cr = (lane >> 4) * 4;

  __shared__ __hip_bfloat16 As[32 * 520];     // 32.5 KB, padded (stride 1040B)
  __shared__ __hip_bfloat16 Bs[2][256 * 64];  // 64 KB, dbuf + chunk-swizzled
  __shared__ float chS[32][2];
  __shared__ float gS[8][2];

  {
    const __hip_bfloat16* wp = WPP + ((long)n * 512 + ch0) * 512;
    const int row = tid >> 4, e0 = (tid & 15) * 32;
#pragma unroll
    for (int q = 0; q < 4; ++q)
      *(s8v*)&As[row * 520 + e0 + q * 8] =
          *(const s8v*)(wp + (long)row * 512 + e0 + q * 8);
  }
  if (tid < 64) chS[tid >> 1][tid & 1] = 0.f;

  const __hip_bfloat16* xb = XT + (long)n * 1024 * 512;
  const int swz = ((lane & 7) ^ (lane >> 3)) * 8;  // source chunk pre-swizzle
  auto STAGE = [&](int it, int buf) {
    const int pcs = it >> 3, kcs = it & 7;
#pragma unroll
    for (int t = 0; t < 4; ++t) {
      const int r0 = wid * 32 + t * 8;
      gload_lds16(xb + (long)(pcs * 256 + r0 + (lane >> 3)) * 512 + kcs * 64 + swz,
                  &Bs[buf][r0 * 64]);
    }
  };

  f32x4 acc[4][4] = {};
  STAGE(0, 0);

#pragma unroll
  for (int pc = 0; pc < 4; ++pc) {
    for (int kc = 0; kc < 8; ++kc) {
      const int it = pc * 8 + kc;
      const int cur = kc & 1;
      asm volatile("s_waitcnt vmcnt(0) lgkmcnt(0)" ::: "memory");
      __builtin_amdgcn_s_barrier();
      __builtin_amdgcn_sched_barrier(0);
      if (it < 31) STAGE(it + 1, cur ^ 1);
#pragma unroll
      for (int ks = 0; ks < 2; ++ks) {
        const int ko = ks * 32 + (lane >> 4) * 8;
        const int g = ks * 4 + (lane >> 4);  // 16B chunk index 0..7
        const s8v a = *(const s8v*)&As[(wm * 16 + cc) * 520 + kc * 64 + ko];
#pragma unroll
        for (int j = 0; j < 4; ++j) {
          const int row = wpx * 64 + j * 16 + cc;
          const s8v b = *(const s8v*)((const char*)&Bs[cur][0] +
                                      ((row << 7) | ((g ^ (cc & 7)) << 4)));
          acc[pc][j] = MFMA_BF16(a, b, acc[pc][j], 0, 0, 0);
        }
      }
    }
  }

  float b2v[4], gwv[4], gbv[4];
#pragma unroll
  for (int r = 0; r < 4; ++r) {
    const int ch = ch0 + wm * 16 + cr + r;
    b2v[r] = b2[n * 512 + ch];
    gwv[r] = gw[ch];
    gbv[r] = gb[ch];
  }
  float s[4] = {}, s2[4] = {};
#pragma unroll
  for (int pc = 0; pc < 4; ++pc)
#pragma unroll
    for (int j = 0; j < 4; ++j)
#pragma unroll
      for (int r = 0; r < 4; ++r) {
        const float v = acc[pc][j][r] + b2v[r];
        acc[pc][j][r] = v;
        s[r] += v;
        s2[r] += v * v;
      }
#pragma unroll
  for (int off = 1; off < 16; off <<= 1)
#pragma unroll
    for (int r = 0; r < 4; ++r) {
      s[r] += __shfl_xor(s[r], off);
      s2[r] += __shfl_xor(s2[r], off);
    }
  __syncthreads();
  if (cc == 0) {
#pragma unroll
    for (int r = 0; r < 4; ++r) {
      atomicAdd(&chS[wm * 16 + cr + r][0], s[r]);
      atomicAdd(&chS[wm * 16 + cr + r][1], s2[r]);
    }
  }
  __syncthreads();
  if (tid < 8) {
    const int g = tid;
    float ts = 0.f, t2 = 0.f;
#pragma unroll
    for (int c = 0; c < 4; ++c) { ts += chS[g * 4 + c][0]; t2 += chS[g * 4 + c][1]; }
    const float mu = ts * (1.f / 4096.f);
    const float var = t2 * (1.f / 4096.f) - mu * mu;
    gS[g][0] = mu;
    gS[g][1] = rsqrtf(var + 1e-5f);
  }
  __syncthreads();

#pragma unroll
  for (int r = 0; r < 4; ++r) {
    const int chl = wm * 16 + cr + r;
    const int ch = ch0 + chl;
    const float mu = gS[chl >> 2][0], rstd = gS[chl >> 2][1];
    const float sc = rstd * gwv[r], sh = gbv[r];
    float* op = out + ((long)n * 512 + ch) * 1024;
    const __hip_bfloat16* xr = Xc + ((long)n * 512 + ch) * 1024;
#pragma unroll
    for (int pc = 0; pc < 4; ++pc)
#pragma unroll
      for (int j = 0; j < 4; ++j) {
        const int px = pc * 256 + wpx * 64 + j * 16 + cc;
        op[px] = (acc[pc][j][r] - mu) * sc + sh + __bfloat162float(xr[px]);
      }
  }
}

extern "C" void kernel_launch(void* const* d_in, const int* in_sizes, int n_in,
                              void* d_out, int out_size, void* d_ws, size_t ws_size,
                              hipStream_t stream) {
  const float* X  = (const float*)d_in[0];
  const float* Wq = (const float*)d_in[1];
  const float* bq = (const float*)d_in[2];
  const float* Wk = (const float*)d_in[3];
  const float* bk = (const float*)d_in[4];
  const float* Wv = (const float*)d_in[5];
  const float* bv = (const float*)d_in[6];
  const float* Wo = (const float*)d_in[7];
  const float* bo = (const float*)d_in[8];
  const float* gw = (const float*)d_in[9];
  const float* gb = (const float*)d_in[10];
  float* out = (float*)d_out;

  char* ws = (char*)d_ws;
  __hip_bfloat16* XT  = (__hip_bfloat16*)(ws + 0);          // 16 MiB [16384][512]
  float*          Part= (float*)(ws + 16777216);            // 16 MiB [1024][64][64] fp32
  __hip_bfloat16* WPP = (__hip_bfloat16*)(ws + 58720256);   // 8 MiB  W'' [16][512][512]
  __hip_bfloat16* WA  = (__hip_bfloat16*)(ws + 68157440);   // 1 MiB  [Wq;Wv]
  __hip_bfloat16* WkT = (__hip_bfloat16*)(ws + 69206016);   // 0.5 MiB
  __hip_bfloat16* WOb = (__hip_bfloat16*)(ws + 69730304);   // 0.5 MiB
  float*          bKV = (float*)(ws + 70254592);            // [1024]
  float*          b2  = (float*)(ws + 70258688);            // [16][512] fp32
  __hip_bfloat16* Xc  = (__hip_bfloat16*)(ws + 75497472);   // 16 MiB [16][512][1024] bf16

  // 1. X -> XT (bf16 [n][p][c]) + Xc (bf16 [n][c][p]) + weight casts
  prep<<<dim3(16, 8, 17), 256, 0, stream>>>(X, XT, Xc, Wq, Wv, Wk, Wo, bq, bv,
                                            WA, WkT, WOb, bKV);
  // 2. fused K/V projection + M-partials (K,V never materialized in HBM)
  kvm<<<1024, 256, 0, stream>>>(WA, XT, bKV, Part);
  // 3. W'' = (Wo * blockdiag(M)) * Wk, b2 = W'*bk + bo  (sums kvm partials)
  wchain<<<dim3(4, 4, 16), 256, 0, stream>>>(WOb, WkT, Part, bk, bo, WPP, b2);
  // 4. fused Y-GEMM + GroupNorm + affine + residual -> out
  ygn<<<256, 512, 0, stream>>>(WPP, XT, b2, Xc, gw, gb, out);
}

// Round 12
// 122.223 us; speedup vs baseline: 1.2073x; 1.2073x over previous
//
#include <hip/hip_runtime.h>
#include <hip/hip_bf16.h>

typedef __attribute__((ext_vector_type(8))) short s8v;
typedef __attribute__((ext_vector_type(4))) short s4v;
typedef __attribute__((ext_vector_type(4))) float f32x4;

#define MFMA_BF16 __builtin_amdgcn_mfma_f32_16x16x32_bf16

__device__ inline void gload_lds16(const __hip_bfloat16* g, __hip_bfloat16* l) {
  __builtin_amdgcn_global_load_lds(
      (const __attribute__((address_space(1))) void*)g,
      (__attribute__((address_space(3))) void*)l, 16, 0, 0);
}

__device__ inline short f2bs(float x) {
  __hip_bfloat16 b = __float2bfloat16(x);
  return *reinterpret_cast<short*>(&b);
}

// ---- prep: (z<16) X[n][c][p] fp32 -> XT[n][p][c] bf16 + Xc[n][c][p] bf16
//      (z==16) weight casts
__global__ __launch_bounds__(256) void prep(const float* __restrict__ X,
                                            __hip_bfloat16* __restrict__ XT,
                                            __hip_bfloat16* __restrict__ Xc,
                                            const float* __restrict__ Wq,
                                            const float* __restrict__ Wv,
                                            const float* __restrict__ Wk,
                                            const float* __restrict__ Wo,
                                            const float* __restrict__ bq,
                                            const float* __restrict__ bv,
                                            __hip_bfloat16* __restrict__ WA,
                                            __hip_bfloat16* __restrict__ WkT,
                                            __hip_bfloat16* __restrict__ WOb,
                                            float* __restrict__ biasKV) {
  const int tid = threadIdx.x;
  if (blockIdx.z == 16) {  // weight casts: 128 blocks x 8 iters x 256 threads
    const int blk = blockIdx.y * 16 + blockIdx.x;
#pragma unroll
    for (int t = 0; t < 8; ++t) {
      const int i = (blk * 8 + t) * 256 + tid;  // < 262144
      WA[i] = __float2bfloat16(Wq[i]);
      WA[262144 + i] = __float2bfloat16(Wv[i]);
      WOb[i] = __float2bfloat16(Wo[i]);
      WkT[i] = __float2bfloat16(Wk[(i & 511) * 512 + (i >> 9)]);
      if (i < 512) { biasKV[i] = bq[i]; biasKV[512 + i] = bv[i]; }
    }
    return;
  }
  __shared__ float tl[64][65];
  const int n = blockIdx.z;
  const int c0 = blockIdx.y * 64, p0 = blockIdx.x * 64;
  const int lr = tid >> 4, lc4 = (tid & 15) * 4;
  const float* Xp = X + ((long)n * 512 + c0) * 1024 + p0;
  __hip_bfloat16* Xcp = Xc + ((long)n * 512 + c0) * 1024 + p0;
#pragma unroll
  for (int i = 0; i < 4; ++i) {
    const int ch = i * 16 + lr;
    const float4 v = *(const float4*)&Xp[(long)ch * 1024 + lc4];
    tl[ch][lc4 + 0] = v.x; tl[ch][lc4 + 1] = v.y;
    tl[ch][lc4 + 2] = v.z; tl[ch][lc4 + 3] = v.w;
    s4v xo;
    xo[0] = f2bs(v.x); xo[1] = f2bs(v.y); xo[2] = f2bs(v.z); xo[3] = f2bs(v.w);
    *(s4v*)&Xcp[(long)ch * 1024 + lc4] = xo;  // straight bf16 copy for residual
  }
  __syncthreads();
  __hip_bfloat16* XTp = XT + ((long)n * 1024 + p0) * 512 + c0;
#pragma unroll
  for (int i = 0; i < 4; ++i) {
    const int px = i * 16 + lr;
    s4v o;
#pragma unroll
    for (int e = 0; e < 4; ++e) o[e] = f2bs(tl[lc4 + e][px]);
    *(s4v*)&XTp[(long)px * 512 + lc4] = o;
  }
}

// ---- kvm: K_h,V_h tiles computed on the fly (never hit HBM) + M-partial ---
// block b=(n,h,t): phase1 dual-A GEMM (K=Wq_h*XTt^T, V=Wv_h*XTt^T, 64x128
// each, shared B-tile); phase2 +bias -> bf16 KS/VS [64][136] LDS; phase3
// M-part = V*K^T over 128 px -> fp32 Part[b][64][64] (transposed [j][i]).
__global__ __launch_bounds__(256) void kvm(const __hip_bfloat16* __restrict__ WA,
                                           const __hip_bfloat16* __restrict__ XT,
                                           const float* __restrict__ bKV,
                                           float* __restrict__ Part) {
  const int b = blockIdx.x;  // 1024: n=b>>6, h=(b>>3)&7, t=b&7
  const int n = b >> 6, h = (b >> 3) & 7, t = b & 7;
  const int tid = threadIdx.x, wid = tid >> 6, lane = tid & 63;
  const int wm = wid >> 1, wn = wid & 1;
  const int cr = (lane >> 4) * 4, cc = lane & 15;

  __shared__ __hip_bfloat16 KS[64 * 136];   // 17 KiB, +8 pad
  __shared__ __hip_bfloat16 VS[64 * 136];   // 17 KiB
  __shared__ float part2[2][4096];          // 32 KiB, overlays staging
  __hip_bfloat16* AqS = (__hip_bfloat16*)&part2[0][0];  //  8 KiB [64][64]
  __hip_bfloat16* AvS = AqS + 64 * 64;                  //  8 KiB
  __hip_bfloat16* BS  = AvS + 64 * 64;                  // 16 KiB [128][64]

  f32x4 aK[2][4] = {}, aV[2][4] = {};

  const int r8 = lane >> 3, b8 = (lane & 7) * 8;
  const __hip_bfloat16* gq = WA + (long)(h * 64 + wid * 16 + r8) * 512 + b8;
  const __hip_bfloat16* gv = gq + (long)512 * 512;
  const __hip_bfloat16* gx = XT + (long)(n * 1024 + t * 128 + wid * 32 + r8) * 512 + b8;

  for (int k0 = 0; k0 < 512; k0 += 64) {
#pragma unroll
    for (int u = 0; u < 2; ++u) {
      gload_lds16(gq + (long)(u * 8) * 512 + k0, &AqS[(wid * 16 + u * 8) * 64]);
      gload_lds16(gv + (long)(u * 8) * 512 + k0, &AvS[(wid * 16 + u * 8) * 64]);
    }
#pragma unroll
    for (int u = 0; u < 4; ++u)
      gload_lds16(gx + (long)(u * 8) * 512 + k0, &BS[(wid * 32 + u * 8) * 64]);
    __syncthreads();
#pragma unroll
    for (int ks = 0; ks < 2; ++ks) {
      const int ko = ks * 32 + (lane >> 4) * 8;
      s8v q[2], v[2], bb[4];
#pragma unroll
      for (int i = 0; i < 2; ++i) {
        q[i] = *(const s8v*)&AqS[(wm * 32 + i * 16 + cc) * 64 + ko];
        v[i] = *(const s8v*)&AvS[(wm * 32 + i * 16 + cc) * 64 + ko];
      }
#pragma unroll
      for (int j = 0; j < 4; ++j)
        bb[j] = *(const s8v*)&BS[(wn * 64 + j * 16 + cc) * 64 + ko];
#pragma unroll
      for (int i = 0; i < 2; ++i)
#pragma unroll
        for (int j = 0; j < 4; ++j) {
          aK[i][j] = MFMA_BF16(q[i], bb[j], aK[i][j], 0, 0, 0);
          aV[i][j] = MFMA_BF16(v[i], bb[j], aV[i][j], 0, 0, 0);
        }
    }
    __syncthreads();
  }

  // phase 2: +bias, bf16 -> KS/VS [ch][px]
#pragma unroll
  for (int i = 0; i < 2; ++i)
#pragma unroll
    for (int r = 0; r < 4; ++r) {
      const int ch = wm * 32 + i * 16 + cr + r;
      const float bk_ = bKV[h * 64 + ch];
      const float bv_ = bKV[512 + h * 64 + ch];
#pragma unroll
      for (int j = 0; j < 4; ++j) {
        const int px = wn * 64 + j * 16 + cc;
        KS[ch * 136 + px] = __float2bfloat16(aK[i][j][r] + bk_);
        VS[ch * 136 + px] = __float2bfloat16(aV[i][j][r] + bv_);
      }
    }
  __syncthreads();

  // phase 3: M-partial = V*K^T over 128 px; wave wid owns px [wid*32,+32)
  f32x4 m[4][4] = {};
  {
    const int pxb = wid * 32 + (lane >> 4) * 8;
    s8v av[4], ak[4];
#pragma unroll
    for (int i = 0; i < 4; ++i)
      av[i] = *(const s8v*)&VS[((lane & 15) + i * 16) * 136 + pxb];
#pragma unroll
    for (int j = 0; j < 4; ++j)
      ak[j] = *(const s8v*)&KS[((lane & 15) + j * 16) * 136 + pxb];
#pragma unroll
    for (int i = 0; i < 4; ++i)
#pragma unroll
      for (int j = 0; j < 4; ++j)
        m[i][j] = MFMA_BF16(av[i], ak[j], m[i][j], 0, 0, 0);
  }
  // 2-stage wave reduction into part2 (staging region is dead)
  if (wid < 2) {
#pragma unroll
    for (int i = 0; i < 4; ++i)
#pragma unroll
      for (int r = 0; r < 4; ++r)
#pragma unroll
        for (int j = 0; j < 4; ++j)
          part2[wid][(i * 16 + cr + r) * 64 + j * 16 + cc] = m[i][j][r];
  }
  __syncthreads();
  if (wid >= 2) {
#pragma unroll
    for (int i = 0; i < 4; ++i)
#pragma unroll
      for (int r = 0; r < 4; ++r)
#pragma unroll
        for (int j = 0; j < 4; ++j)
          part2[wid - 2][(i * 16 + cr + r) * 64 + j * 16 + cc] += m[i][j][r];
  }
  __syncthreads();
  float* outp = Part + (long)b * 4096;
  for (int e = tid; e < 4096; e += 256)
    outp[(e & 63) * 64 + (e >> 6)] = part2[0][e] + part2[1][e];  // [j][i]
}

// ---- mred: Mt[n,h] = sum of the 8 fp32 kvm partials, bf16 ------------------
// 512 blocks x 256 thr: block handles quarter of one (n,h); thread sums 4 elems.
__global__ __launch_bounds__(256) void mred(const float* __restrict__ Part,
                                            __hip_bfloat16* __restrict__ Mt) {
  const int b = blockIdx.x;            // 512: nh = b>>2, quarter = b&3
  const int nh = b >> 2;
  const int e = (b & 3) * 1024 + threadIdx.x * 4;
  const float* P0 = Part + (long)nh * 8 * 4096 + e;
  float4 s = *(const float4*)P0;
#pragma unroll
  for (int p = 1; p < 8; ++p) {
    const float4 x = *(const float4*)(P0 + (long)p * 4096);
    s.x += x.x; s.y += x.y; s.z += x.z; s.w += x.w;
  }
  s4v o;
  o[0] = f2bs(s.x); o[1] = f2bs(s.y); o[2] = f2bs(s.z); o[3] = f2bs(s.w);
  *(s4v*)&Mt[(long)nh * 4096 + e] = o;
}

// ---- wchain: W''[n] = (Wo * blockdiag(M[n])) * Wk,  b2[n] = W'*bk + bo ----
// (R10 version — reads Mt bf16; simple barriers, 66 KB LDS, 2 blocks/CU)
__global__ __launch_bounds__(256) void wchain(const __hip_bfloat16* __restrict__ WOb,
                                              const __hip_bfloat16* __restrict__ WkT,
                                              const __hip_bfloat16* __restrict__ Mt,
                                              const float* __restrict__ bk,
                                              const float* __restrict__ bo,
                                              __hip_bfloat16* __restrict__ WPP,
                                              float* __restrict__ b2out) {
  const int c0 = blockIdx.x * 128, o0 = blockIdx.y * 128, n = blockIdx.z;
  const int tid = threadIdx.x, wid = tid >> 6, lane = tid & 63;
  const int wm = wid >> 1, wn = wid & 1;
  const int cr = (lane >> 4) * 4, cc = lane & 15;

  __shared__ __hip_bfloat16 WoS[128 * 64];
  __shared__ __hip_bfloat16 WkS[128 * 64];
  __shared__ __hip_bfloat16 MtS[64 * 64];
  __shared__ __hip_bfloat16 W1S[128 * 64];
  __shared__ float bkS[512];

  if (tid < 128) *(float4*)&bkS[tid * 4] = *(const float4*)&bk[tid * 4];

  f32x4 acc2[4][4] = {};
  float bacc = 0.f;
  const int r8 = lane >> 3, b8 = (lane & 7) * 8;

  for (int h = 0; h < 8; ++h) {
#pragma unroll
    for (int t = 0; t < 4; ++t) {
      const int row = wid * 32 + t * 8;
      gload_lds16(WOb + (long)(o0 + row + r8) * 512 + h * 64 + b8, &WoS[row * 64]);
      gload_lds16(WkT + (long)(c0 + row + r8) * 512 + h * 64 + b8, &WkS[row * 64]);
    }
    {
      const __hip_bfloat16* mg = Mt + ((long)n * 8 + h) * 4096;
      gload_lds16(mg + wid * 512 + lane * 8, &MtS[wid * 512]);
      gload_lds16(mg + 2048 + wid * 512 + lane * 8, &MtS[2048 + wid * 512]);
    }
    __syncthreads();

    f32x4 acc1[2][4] = {};
#pragma unroll
    for (int ks = 0; ks < 2; ++ks) {
      const int ko = ks * 32 + (lane >> 4) * 8;
      s8v aj[2], bw[4];
#pragma unroll
      for (int i = 0; i < 2; ++i)
        aj[i] = *(const s8v*)&MtS[(wn * 32 + i * 16 + cc) * 64 + ko];
#pragma unroll
      for (int t = 0; t < 4; ++t)
        bw[t] = *(const s8v*)&WoS[(wm * 64 + t * 16 + cc) * 64 + ko];
#pragma unroll
      for (int i = 0; i < 2; ++i)
#pragma unroll
        for (int t = 0; t < 4; ++t)
          acc1[i][t] = MFMA_BF16(aj[i], bw[t], acc1[i][t], 0, 0, 0);
    }
#pragma unroll
    for (int i = 0; i < 2; ++i)
#pragma unroll
      for (int t = 0; t < 4; ++t) {
        const int o = wm * 64 + t * 16 + cc;
        const int jb = wn * 32 + i * 16 + cr;
        s4v p;
#pragma unroll
        for (int r = 0; r < 4; ++r) p[r] = f2bs(acc1[i][t][r]);
        *(s4v*)((char*)W1S + ((o * 128 + jb * 2) ^ ((o & 7) << 4))) = p;
      }
    __syncthreads();

#pragma unroll
    for (int ks = 0; ks < 2; ++ks) {
      const int ko = ks * 32 + (lane >> 4) * 8;
      s8v a2[4], bw[4];
#pragma unroll
      for (int i = 0; i < 4; ++i) {
        const int o = wm * 64 + i * 16 + cc;
        a2[i] = *(const s8v*)((char*)W1S + ((o * 128 + ko * 2) ^ ((o & 7) << 4)));
      }
#pragma unroll
      for (int t = 0; t < 4; ++t)
        bw[t] = *(const s8v*)&WkS[(wn * 64 + t * 16 + cc) * 64 + ko];
#pragma unroll
      for (int i = 0; i < 4; ++i)
#pragma unroll
        for (int t = 0; t < 4; ++t)
          acc2[i][t] = MFMA_BF16(a2[i], bw[t], acc2[i][t], 0, 0, 0);
    }

    if (c0 == 0) {
      const int o = tid >> 1, half = tid & 1;
      float s = 0.f;
#pragma unroll
      for (int q = 0; q < 4; ++q) {
        const int jb = half * 64 + q * 16;
        const s8v w = *(const s8v*)((char*)W1S + ((o * 128 + jb) ^ ((o & 7) << 4)));
        const __hip_bfloat16* wb = (const __hip_bfloat16*)&w;
#pragma unroll
        for (int e = 0; e < 8; ++e)
          s += __bfloat162float(wb[e]) * bkS[h * 64 + half * 32 + q * 8 + e];
      }
      bacc += s;
    }
    __syncthreads();
  }

#pragma unroll
  for (int i = 0; i < 4; ++i)
#pragma unroll
    for (int r = 0; r < 4; ++r)
#pragma unroll
      for (int t = 0; t < 4; ++t)
        WPP[((long)n * 512 + o0 + wm * 64 + i * 16 + cr + r) * 512 +
            c0 + wn * 64 + t * 16 + cc] = __float2bfloat16(acc2[i][t][r]);
  if (c0 == 0) {
    const float tot = bacc + __shfl_xor(bacc, 1);
    if ((tid & 1) == 0) {
      const int o = tid >> 1;
      b2out[n * 512 + o0 + o] = tot + bo[o0 + o];
    }
  }
}

// ---- ygn v2: fused Y-GEMM + GroupNorm + residual, conflict-free ----------
__global__ __launch_bounds__(512) void ygn(const __hip_bfloat16* __restrict__ WPP,
                                           const __hip_bfloat16* __restrict__ XT,
                                           const float* __restrict__ b2,
                                           const __hip_bfloat16* __restrict__ Xc,
                                           const float* __restrict__ gw,
                                           const float* __restrict__ gb,
                                           float* __restrict__ out) {
  const int id = blockIdx.x;            // 256 blocks
  const int xcd = id & 7, slot = id >> 3;
  const int n = xcd * 2 + (slot >> 4);  // 2 n per XCD -> XT[n] L2-resident
  const int ch0 = (slot & 15) * 32;
  const int tid = threadIdx.x, wid = tid >> 6, lane = tid & 63;
  const int wm = wid & 1, wpx = wid >> 1;
  const int cc = lane & 15, cr = (lane >> 4) * 4;

  __shared__ __hip_bfloat16 As[32 * 520];     // 32.5 KB, padded (stride 1040B)
  __shared__ __hip_bfloat16 Bs[2][256 * 64];  // 64 KB, dbuf + chunk-swizzled
  __shared__ float chS[32][2];
  __shared__ float gS[8][2];

  {
    const __hip_bfloat16* wp = WPP + ((long)n * 512 + ch0) * 512;
    const int row = tid >> 4, e0 = (tid & 15) * 32;
#pragma unroll
    for (int q = 0; q < 4; ++q)
      *(s8v*)&As[row * 520 + e0 + q * 8] =
          *(const s8v*)(wp + (long)row * 512 + e0 + q * 8);
  }
  if (tid < 64) chS[tid >> 1][tid & 1] = 0.f;

  const __hip_bfloat16* xb = XT + (long)n * 1024 * 512;
  const int swz = ((lane & 7) ^ (lane >> 3)) * 8;  // source chunk pre-swizzle
  auto STAGE = [&](int it, int buf) {
    const int pcs = it >> 3, kcs = it & 7;
#pragma unroll
    for (int t = 0; t < 4; ++t) {
      const int r0 = wid * 32 + t * 8;
      gload_lds16(xb + (long)(pcs * 256 + r0 + (lane >> 3)) * 512 + kcs * 64 + swz,
                  &Bs[buf][r0 * 64]);
    }
  };

  f32x4 acc[4][4] = {};
  STAGE(0, 0);

#pragma unroll
  for (int pc = 0; pc < 4; ++pc) {
    for (int kc = 0; kc < 8; ++kc) {
      const int it = pc * 8 + kc;
      const int cur = kc & 1;
      asm volatile("s_waitcnt vmcnt(0) lgkmcnt(0)" ::: "memory");
      __builtin_amdgcn_s_barrier();
      __builtin_amdgcn_sched_barrier(0);
      if (it < 31) STAGE(it + 1, cur ^ 1);
#pragma unroll
      for (int ks = 0; ks < 2; ++ks) {
        const int ko = ks * 32 + (lane >> 4) * 8;
        const int g = ks * 4 + (lane >> 4);  // 16B chunk index 0..7
        const s8v a = *(const s8v*)&As[(wm * 16 + cc) * 520 + kc * 64 + ko];
#pragma unroll
        for (int j = 0; j < 4; ++j) {
          const int row = wpx * 64 + j * 16 + cc;
          const s8v b = *(const s8v*)((const char*)&Bs[cur][0] +
                                      ((row << 7) | ((g ^ (cc & 7)) << 4)));
          acc[pc][j] = MFMA_BF16(a, b, acc[pc][j], 0, 0, 0);
        }
      }
    }
  }

  float b2v[4], gwv[4], gbv[4];
#pragma unroll
  for (int r = 0; r < 4; ++r) {
    const int ch = ch0 + wm * 16 + cr + r;
    b2v[r] = b2[n * 512 + ch];
    gwv[r] = gw[ch];
    gbv[r] = gb[ch];
  }
  float s[4] = {}, s2[4] = {};
#pragma unroll
  for (int pc = 0; pc < 4; ++pc)
#pragma unroll
    for (int j = 0; j < 4; ++j)
#pragma unroll
      for (int r = 0; r < 4; ++r) {
        const float v = acc[pc][j][r] + b2v[r];
        acc[pc][j][r] = v;
        s[r] += v;
        s2[r] += v * v;
      }
#pragma unroll
  for (int off = 1; off < 16; off <<= 1)
#pragma unroll
    for (int r = 0; r < 4; ++r) {
      s[r] += __shfl_xor(s[r], off);
      s2[r] += __shfl_xor(s2[r], off);
    }
  __syncthreads();
  if (cc == 0) {
#pragma unroll
    for (int r = 0; r < 4; ++r) {
      atomicAdd(&chS[wm * 16 + cr + r][0], s[r]);
      atomicAdd(&chS[wm * 16 + cr + r][1], s2[r]);
    }
  }
  __syncthreads();
  if (tid < 8) {
    const int g = tid;
    float ts = 0.f, t2 = 0.f;
#pragma unroll
    for (int c = 0; c < 4; ++c) { ts += chS[g * 4 + c][0]; t2 += chS[g * 4 + c][1]; }
    const float mu = ts * (1.f / 4096.f);
    const float var = t2 * (1.f / 4096.f) - mu * mu;
    gS[g][0] = mu;
    gS[g][1] = rsqrtf(var + 1e-5f);
  }
  __syncthreads();

#pragma unroll
  for (int r = 0; r < 4; ++r) {
    const int chl = wm * 16 + cr + r;
    const int ch = ch0 + chl;
    const float mu = gS[chl >> 2][0], rstd = gS[chl >> 2][1];
    const float sc = rstd * gwv[r], sh = gbv[r];
    float* op = out + ((long)n * 512 + ch) * 1024;
    const __hip_bfloat16* xr = Xc + ((long)n * 512 + ch) * 1024;
#pragma unroll
    for (int pc = 0; pc < 4; ++pc)
#pragma unroll
      for (int j = 0; j < 4; ++j) {
        const int px = pc * 256 + wpx * 64 + j * 16 + cc;
        op[px] = (acc[pc][j][r] - mu) * sc + sh + __bfloat162float(xr[px]);
      }
  }
}

extern "C" void kernel_launch(void* const* d_in, const int* in_sizes, int n_in,
                              void* d_out, int out_size, void* d_ws, size_t ws_size,
                              hipStream_t stream) {
  const float* X  = (const float*)d_in[0];
  const float* Wq = (const float*)d_in[1];
  const float* bq = (const float*)d_in[2];
  const float* Wk = (const float*)d_in[3];
  const float* bk = (const float*)d_in[4];
  const float* Wv = (const float*)d_in[5];
  const float* bv = (const float*)d_in[6];
  const float* Wo = (const float*)d_in[7];
  const float* bo = (const float*)d_in[8];
  const float* gw = (const float*)d_in[9];
  const float* gb = (const float*)d_in[10];
  float* out = (float*)d_out;

  char* ws = (char*)d_ws;
  __hip_bfloat16* XT  = (__hip_bfloat16*)(ws + 0);          // 16 MiB [16384][512]
  float*          Part= (float*)(ws + 16777216);            // 16 MiB [1024][64][64] fp32
  __hip_bfloat16* Mt  = (__hip_bfloat16*)(ws + 33554432);   // 1 MiB  [16][8][64][64]
  __hip_bfloat16* WPP = (__hip_bfloat16*)(ws + 58720256);   // 8 MiB  W'' [16][512][512]
  __hip_bfloat16* WA  = (__hip_bfloat16*)(ws + 68157440);   // 1 MiB  [Wq;Wv]
  __hip_bfloat16* WkT = (__hip_bfloat16*)(ws + 69206016);   // 0.5 MiB
  __hip_bfloat16* WOb = (__hip_bfloat16*)(ws + 69730304);   // 0.5 MiB
  float*          bKV = (float*)(ws + 70254592);            // [1024]
  float*          b2  = (float*)(ws + 70258688);            // [16][512] fp32
  __hip_bfloat16* Xc  = (__hip_bfloat16*)(ws + 75497472);   // 16 MiB [16][512][1024] bf16

  // 1. X -> XT (bf16 [n][p][c]) + Xc (bf16 [n][c][p]) + weight casts
  prep<<<dim3(16, 8, 17), 256, 0, stream>>>(X, XT, Xc, Wq, Wv, Wk, Wo, bq, bv,
                                            WA, WkT, WOb, bKV);
  // 2. fused K/V projection + M-partials (K,V never materialized in HBM)
  kvm<<<1024, 256, 0, stream>>>(WA, XT, bKV, Part);
  // 3. Mt = sum of the 8 partials per (n,h), bf16
  mred<<<512, 256, 0, stream>>>(Part, Mt);
  // 4. W'' = (Wo * blockdiag(M)) * Wk, b2 = W'*bk + bo  (fused chain)
  wchain<<<dim3(4, 4, 16), 256, 0, stream>>>(WOb, WkT, Mt, bk, bo, WPP, b2);
  // 5. fused Y-GEMM + GroupNorm + affine + residual -> out
  ygn<<<256, 512, 0, stream>>>(WPP, XT, b2, Xc, gw, gb, out);
}

// Round 13
// 118.888 us; speedup vs baseline: 1.2412x; 1.0281x over previous
//
#include <hip/hip_runtime.h>
#include <hip/hip_bf16.h>

typedef __attribute__((ext_vector_type(8))) short s8v;
typedef __attribute__((ext_vector_type(4))) short s4v;
typedef __attribute__((ext_vector_type(4))) float f32x4;

#define MFMA_BF16 __builtin_amdgcn_mfma_f32_16x16x32_bf16

__device__ inline void gload_lds16(const __hip_bfloat16* g, __hip_bfloat16* l) {
  __builtin_amdgcn_global_load_lds(
      (const __attribute__((address_space(1))) void*)g,
      (__attribute__((address_space(3))) void*)l, 16, 0, 0);
}

__device__ inline short f2bs(float x) {
  __hip_bfloat16 b = __float2bfloat16(x);
  return *reinterpret_cast<short*>(&b);
}

__device__ inline void storeC(float* p, float v) { *p = v; }
__device__ inline void storeC(__hip_bfloat16* p, float v) { *p = __float2bfloat16(v); }

// ---- prep: (z<16) X[n][c][p] fp32 -> XT[n][p][c] bf16 + Xc[n][c][p] bf16
//      (z==16) weight casts
__global__ __launch_bounds__(256) void prep(const float* __restrict__ X,
                                            __hip_bfloat16* __restrict__ XT,
                                            __hip_bfloat16* __restrict__ Xc,
                                            const float* __restrict__ Wq,
                                            const float* __restrict__ Wv,
                                            const float* __restrict__ Wk,
                                            const float* __restrict__ Wo,
                                            const float* __restrict__ bq,
                                            const float* __restrict__ bv,
                                            __hip_bfloat16* __restrict__ WA,
                                            __hip_bfloat16* __restrict__ WkT,
                                            __hip_bfloat16* __restrict__ WOb,
                                            float* __restrict__ biasKV) {
  const int tid = threadIdx.x;
  if (blockIdx.z == 16) {  // weight casts: 128 blocks x 8 iters x 256 threads
    const int blk = blockIdx.y * 16 + blockIdx.x;
#pragma unroll
    for (int t = 0; t < 8; ++t) {
      const int i = (blk * 8 + t) * 256 + tid;  // < 262144
      WA[i] = __float2bfloat16(Wq[i]);
      WA[262144 + i] = __float2bfloat16(Wv[i]);
      WOb[i] = __float2bfloat16(Wo[i]);
      WkT[i] = __float2bfloat16(Wk[(i & 511) * 512 + (i >> 9)]);
      if (i < 512) { biasKV[i] = bq[i]; biasKV[512 + i] = bv[i]; }
    }
    return;
  }
  __shared__ float tl[64][65];
  const int n = blockIdx.z;
  const int c0 = blockIdx.y * 64, p0 = blockIdx.x * 64;
  const int lr = tid >> 4, lc4 = (tid & 15) * 4;
  const float* Xp = X + ((long)n * 512 + c0) * 1024 + p0;
  __hip_bfloat16* Xcp = Xc + ((long)n * 512 + c0) * 1024 + p0;
#pragma unroll
  for (int i = 0; i < 4; ++i) {
    const int ch = i * 16 + lr;
    const float4 v = *(const float4*)&Xp[(long)ch * 1024 + lc4];
    tl[ch][lc4 + 0] = v.x; tl[ch][lc4 + 1] = v.y;
    tl[ch][lc4 + 2] = v.z; tl[ch][lc4 + 3] = v.w;
    s4v xo;
    xo[0] = f2bs(v.x); xo[1] = f2bs(v.y); xo[2] = f2bs(v.z); xo[3] = f2bs(v.w);
    *(s4v*)&Xcp[(long)ch * 1024 + lc4] = xo;  // straight bf16 copy for residual
  }
  __syncthreads();
  __hip_bfloat16* XTp = XT + ((long)n * 1024 + p0) * 512 + c0;
#pragma unroll
  for (int i = 0; i < 4; ++i) {
    const int px = i * 16 + lr;
    s4v o;
#pragma unroll
    for (int e = 0; e < 4; ++e) o[e] = f2bs(tl[lc4 + e][px]);
    *(s4v*)&XTp[(long)px * 512 + lc4] = o;
  }
}

// ---------------- NT GEMM: C[m][n] = sum_k A[m][k]*B[n][k] (+row bias) -----
// 128x128 tile, 4 waves (2x2), BK=64, global_load_lds staging (m97 structure).
// SWZ==1 (KV shape: 128 x-tiles, 8 y-tiles): XCD-contiguous decode.
template <typename OutT, bool BROW, int SWZ>
__global__ __launch_bounds__(256) void gemm_nt(
    const __hip_bfloat16* __restrict__ A, long strideA,
    const __hip_bfloat16* __restrict__ B, long strideB,
    OutT* __restrict__ C, long strideC, int K, int ldc,
    const float* __restrict__ brow, long strideBrow) {
  int bx, by, bz;
  if (SWZ == 1) {
    const int id = blockIdx.x;
    const int xcd = id & 7, local = id >> 3;   // 128 blocks per XCD
    bx = xcd * 16 + (local >> 3);              // 16 x-tiles per XCD
    by = local & 7;                            // y fastest: B-panel reuse
    bz = 0;
  } else {
    bx = blockIdx.x; by = blockIdx.y; bz = blockIdx.z;
  }
  A += bz * strideA;
  B += bz * strideB;
  C += bz * strideC;
  const int m0 = by * 128;
  const int n0 = bx * 128;
  const int tid = threadIdx.x;
  const int wid = tid >> 6, lane = tid & 63;
  const int wm = wid >> 1, wn = wid & 1;

  __shared__ __hip_bfloat16 As[128 * 64];
  __shared__ __hip_bfloat16 Bs[128 * 64];

  f32x4 acc[4][4] = {};

  const __hip_bfloat16* gA0 = A + (long)(m0 + wid * 32 + (lane >> 3)) * K + (lane & 7) * 8;
  const __hip_bfloat16* gB0 = B + (long)(n0 + wid * 32 + (lane >> 3)) * K + (lane & 7) * 8;

  for (int k0 = 0; k0 < K; k0 += 64) {
#pragma unroll
    for (int t = 0; t < 4; ++t) {
      gload_lds16(gA0 + (long)t * 8 * K + k0, &As[(wid * 32 + t * 8) * 64]);
      gload_lds16(gB0 + (long)t * 8 * K + k0, &Bs[(wid * 32 + t * 8) * 64]);
    }
    __syncthreads();
#pragma unroll
    for (int ks = 0; ks < 2; ++ks) {
      const int koff = ks * 32 + (lane >> 4) * 8;
      s8v a[4], b[4];
#pragma unroll
      for (int i = 0; i < 4; ++i)
        a[i] = *(const s8v*)&As[(wm * 64 + i * 16 + (lane & 15)) * 64 + koff];
#pragma unroll
      for (int j = 0; j < 4; ++j)
        b[j] = *(const s8v*)&Bs[(wn * 64 + j * 16 + (lane & 15)) * 64 + koff];
#pragma unroll
      for (int i = 0; i < 4; ++i)
#pragma unroll
        for (int j = 0; j < 4; ++j)
          acc[i][j] = MFMA_BF16(a[i], b[j], acc[i][j], 0, 0, 0);
    }
    __syncthreads();
  }

  const int cr = (lane >> 4) * 4;
  const int cc = lane & 15;
#pragma unroll
  for (int i = 0; i < 4; ++i) {
#pragma unroll
    for (int r = 0; r < 4; ++r) {
      const int gm = m0 + wm * 64 + i * 16 + cr + r;
      const float rb = BROW ? brow[bz * strideBrow + gm] : 0.f;
#pragma unroll
      for (int j = 0; j < 4; ++j) {
        const int gn = n0 + wn * 64 + j * 16 + cc;
        storeC(&C[(long)gm * ldc + gn], acc[i][j][r] + rb);
      }
    }
  }
}

// -------- Mt[n,h][j][i] = (V_h K_h^T)[i][j] bf16 (K-reduce 1024, 8 waves) --
__global__ __launch_bounds__(512) void gemm_vkT(const __hip_bfloat16* __restrict__ V,
                                                const __hip_bfloat16* __restrict__ Kk,
                                                __hip_bfloat16* __restrict__ Mt) {
  const int n = blockIdx.x >> 3, h = blockIdx.x & 7;
  const int tid = threadIdx.x, wid = tid >> 6, lane = tid & 63;
  f32x4 acc[4][4] = {};
  const long colbase = (long)n * 1024 + wid * 128 + (lane >> 4) * 8;
  const __hip_bfloat16* Vb = V + (long)(h * 64 + (lane & 15)) * 16384 + colbase;
  const __hip_bfloat16* Kb = Kk + (long)(h * 64 + (lane & 15)) * 16384 + colbase;
#pragma unroll
  for (int kk = 0; kk < 128; kk += 32) {
    s8v a[4], b[4];
#pragma unroll
    for (int i = 0; i < 4; ++i) a[i] = *(const s8v*)(Vb + (long)i * 16 * 16384 + kk);
#pragma unroll
    for (int j = 0; j < 4; ++j) b[j] = *(const s8v*)(Kb + (long)j * 16 * 16384 + kk);
#pragma unroll
    for (int i = 0; i < 4; ++i)
#pragma unroll
      for (int j = 0; j < 4; ++j) acc[i][j] = MFMA_BF16(a[i], b[j], acc[i][j], 0, 0, 0);
  }
  __shared__ float part[4][4096];
  const int cr = (lane >> 4) * 4, cc = lane & 15;
  if (wid < 4) {
#pragma unroll
    for (int i = 0; i < 4; ++i)
#pragma unroll
      for (int r = 0; r < 4; ++r)
#pragma unroll
        for (int j = 0; j < 4; ++j)
          part[wid][(i * 16 + cr + r) * 64 + j * 16 + cc] = acc[i][j][r];
  }
  __syncthreads();
  if (wid >= 4) {
#pragma unroll
    for (int i = 0; i < 4; ++i)
#pragma unroll
      for (int r = 0; r < 4; ++r)
#pragma unroll
        for (int j = 0; j < 4; ++j)
          part[wid - 4][(i * 16 + cr + r) * 64 + j * 16 + cc] += acc[i][j][r];
  }
  __syncthreads();
  __hip_bfloat16* outp = Mt + ((long)n * 8 + h) * 4096;
  for (int e = tid; e < 4096; e += 512) {
    const float sum = part[0][e] + part[1][e] + part[2][e] + part[3][e];
    outp[(e & 63) * 64 + (e >> 6)] = __float2bfloat16(sum);  // Mt[j][i]=M[i][j]
  }
}

// ---- wchain: W''[n] = (Wo * blockdiag(M[n])) * Wk,  b2[n] = W'*bk + bo ----
// (R6/R10 version — simple barriers, 66 KB LDS, 2 blocks/CU)
__global__ __launch_bounds__(256) void wchain(const __hip_bfloat16* __restrict__ WOb,
                                              const __hip_bfloat16* __restrict__ WkT,
                                              const __hip_bfloat16* __restrict__ Mt,
                                              const float* __restrict__ bk,
                                              const float* __restrict__ bo,
                                              __hip_bfloat16* __restrict__ WPP,
                                              float* __restrict__ b2out) {
  const int c0 = blockIdx.x * 128, o0 = blockIdx.y * 128, n = blockIdx.z;
  const int tid = threadIdx.x, wid = tid >> 6, lane = tid & 63;
  const int wm = wid >> 1, wn = wid & 1;
  const int cr = (lane >> 4) * 4, cc = lane & 15;

  __shared__ __hip_bfloat16 WoS[128 * 64];
  __shared__ __hip_bfloat16 WkS[128 * 64];
  __shared__ __hip_bfloat16 MtS[64 * 64];
  __shared__ __hip_bfloat16 W1S[128 * 64];
  __shared__ float bkS[512];

  if (tid < 128) *(float4*)&bkS[tid * 4] = *(const float4*)&bk[tid * 4];

  f32x4 acc2[4][4] = {};
  float bacc = 0.f;
  const int r8 = lane >> 3, b8 = (lane & 7) * 8;

  for (int h = 0; h < 8; ++h) {
#pragma unroll
    for (int t = 0; t < 4; ++t) {
      const int row = wid * 32 + t * 8;
      gload_lds16(WOb + (long)(o0 + row + r8) * 512 + h * 64 + b8, &WoS[row * 64]);
      gload_lds16(WkT + (long)(c0 + row + r8) * 512 + h * 64 + b8, &WkS[row * 64]);
    }
    {
      const __hip_bfloat16* mg = Mt + ((long)n * 8 + h) * 4096;
      gload_lds16(mg + wid * 512 + lane * 8, &MtS[wid * 512]);
      gload_lds16(mg + 2048 + wid * 512 + lane * 8, &MtS[2048 + wid * 512]);
    }
    __syncthreads();

    f32x4 acc1[2][4] = {};
#pragma unroll
    for (int ks = 0; ks < 2; ++ks) {
      const int ko = ks * 32 + (lane >> 4) * 8;
      s8v aj[2], bw[4];
#pragma unroll
      for (int i = 0; i < 2; ++i)
        aj[i] = *(const s8v*)&MtS[(wn * 32 + i * 16 + cc) * 64 + ko];
#pragma unroll
      for (int t = 0; t < 4; ++t)
        bw[t] = *(const s8v*)&WoS[(wm * 64 + t * 16 + cc) * 64 + ko];
#pragma unroll
      for (int i = 0; i < 2; ++i)
#pragma unroll
        for (int t = 0; t < 4; ++t)
          acc1[i][t] = MFMA_BF16(aj[i], bw[t], acc1[i][t], 0, 0, 0);
    }
#pragma unroll
    for (int i = 0; i < 2; ++i)
#pragma unroll
      for (int t = 0; t < 4; ++t) {
        const int o = wm * 64 + t * 16 + cc;
        const int jb = wn * 32 + i * 16 + cr;
        s4v p;
#pragma unroll
        for (int r = 0; r < 4; ++r) p[r] = f2bs(acc1[i][t][r]);
        *(s4v*)((char*)W1S + ((o * 128 + jb * 2) ^ ((o & 7) << 4))) = p;
      }
    __syncthreads();

#pragma unroll
    for (int ks = 0; ks < 2; ++ks) {
      const int ko = ks * 32 + (lane >> 4) * 8;
      s8v a2[4], bw[4];
#pragma unroll
      for (int i = 0; i < 4; ++i) {
        const int o = wm * 64 + i * 16 + cc;
        a2[i] = *(const s8v*)((char*)W1S + ((o * 128 + ko * 2) ^ ((o & 7) << 4)));
      }
#pragma unroll
      for (int t = 0; t < 4; ++t)
        bw[t] = *(const s8v*)&WkS[(wn * 64 + t * 16 + cc) * 64 + ko];
#pragma unroll
      for (int i = 0; i < 4; ++i)
#pragma unroll
        for (int t = 0; t < 4; ++t)
          acc2[i][t] = MFMA_BF16(a2[i], bw[t], acc2[i][t], 0, 0, 0);
    }

    if (c0 == 0) {
      const int o = tid >> 1, half = tid & 1;
      float s = 0.f;
#pragma unroll
      for (int q = 0; q < 4; ++q) {
        const int jb = half * 64 + q * 16;
        const s8v w = *(const s8v*)((char*)W1S + ((o * 128 + jb) ^ ((o & 7) << 4)));
        const __hip_bfloat16* wb = (const __hip_bfloat16*)&w;
#pragma unroll
        for (int e = 0; e < 8; ++e)
          s += __bfloat162float(wb[e]) * bkS[h * 64 + half * 32 + q * 8 + e];
      }
      bacc += s;
    }
    __syncthreads();
  }

#pragma unroll
  for (int i = 0; i < 4; ++i)
#pragma unroll
    for (int r = 0; r < 4; ++r)
#pragma unroll
      for (int t = 0; t < 4; ++t)
        WPP[((long)n * 512 + o0 + wm * 64 + i * 16 + cr + r) * 512 +
            c0 + wn * 64 + t * 16 + cc] = __float2bfloat16(acc2[i][t][r]);
  if (c0 == 0) {
    const float tot = bacc + __shfl_xor(bacc, 1);
    if ((tid & 1) == 0) {
      const int o = tid >> 1;
      b2out[n * 512 + o0 + o] = tot + bo[o0 + o];
    }
  }
}

// ---- ygn v3: fused Y-GEMM + GroupNorm + residual ---------------------------
// v2 conflict fixes kept (padded As, both-sides B chunk swizzle, XCD n-group);
// Bs single-buffered + plain 2-barrier m97 pattern -> 65 KB LDS, 2 blocks/CU:
// cross-block TLP hides staging (m114) instead of the 1-block manual pipeline.
__global__ __launch_bounds__(512) void ygn(const __hip_bfloat16* __restrict__ WPP,
                                           const __hip_bfloat16* __restrict__ XT,
                                           const float* __restrict__ b2,
                                           const __hip_bfloat16* __restrict__ Xc,
                                           const float* __restrict__ gw,
                                           const float* __restrict__ gb,
                                           float* __restrict__ out) {
  const int id = blockIdx.x;            // 256 blocks
  const int xcd = id & 7, slot = id >> 3;
  const int n = xcd * 2 + (slot >> 4);  // 2 n per XCD -> XT[n] L2-resident
  const int ch0 = (slot & 15) * 32;
  const int tid = threadIdx.x, wid = tid >> 6, lane = tid & 63;
  const int wm = wid & 1, wpx = wid >> 1;
  const int cc = lane & 15, cr = (lane >> 4) * 4;

  __shared__ __hip_bfloat16 As[32 * 520];     // 32.5 KB, padded (stride 1040B)
  __shared__ __hip_bfloat16 Bs[256 * 64];     // 32 KB, single buf, swizzled
  __shared__ float chS[32][2];
  __shared__ float gS[8][2];

  // reg-stage A once with +8 pad: thread -> row tid>>4, 32 elems
  {
    const __hip_bfloat16* wp = WPP + ((long)n * 512 + ch0) * 512;
    const int row = tid >> 4, e0 = (tid & 15) * 32;
#pragma unroll
    for (int q = 0; q < 4; ++q)
      *(s8v*)&As[row * 520 + e0 + q * 8] =
          *(const s8v*)(wp + (long)row * 512 + e0 + q * 8);
  }
  if (tid < 64) chS[tid >> 1][tid & 1] = 0.f;

  const __hip_bfloat16* xb = XT + (long)n * 1024 * 512;
  const int swz = ((lane & 7) ^ (lane >> 3)) * 8;  // source chunk pre-swizzle

  f32x4 acc[4][4] = {};

#pragma unroll
  for (int pc = 0; pc < 4; ++pc) {
    for (int kc = 0; kc < 8; ++kc) {
      // stage B: 256 px rows x 64 k, both-sides chunk swizzle
#pragma unroll
      for (int t = 0; t < 4; ++t) {
        const int r0 = wid * 32 + t * 8;
        gload_lds16(xb + (long)(pc * 256 + r0 + (lane >> 3)) * 512 + kc * 64 + swz,
                    &Bs[r0 * 64]);
      }
      __syncthreads();
#pragma unroll
      for (int ks = 0; ks < 2; ++ks) {
        const int ko = ks * 32 + (lane >> 4) * 8;
        const int g = ks * 4 + (lane >> 4);  // 16B chunk index 0..7
        const s8v a = *(const s8v*)&As[(wm * 16 + cc) * 520 + kc * 64 + ko];
#pragma unroll
        for (int j = 0; j < 4; ++j) {
          const int row = wpx * 64 + j * 16 + cc;
          const s8v b = *(const s8v*)((const char*)&Bs[0] +
                                      ((row << 7) | ((g ^ (cc & 7)) << 4)));
          acc[pc][j] = MFMA_BF16(a, b, acc[pc][j], 0, 0, 0);
        }
      }
      __syncthreads();
    }
  }

  // + b2 bias, then per-lane partial stats (each lane: 4 ch x 16 px)
  float b2v[4], gwv[4], gbv[4];
#pragma unroll
  for (int r = 0; r < 4; ++r) {
    const int ch = ch0 + wm * 16 + cr + r;
    b2v[r] = b2[n * 512 + ch];
    gwv[r] = gw[ch];
    gbv[r] = gb[ch];
  }
  float s[4] = {}, s2[4] = {};
#pragma unroll
  for (int pc = 0; pc < 4; ++pc)
#pragma unroll
    for (int j = 0; j < 4; ++j)
#pragma unroll
      for (int r = 0; r < 4; ++r) {
        const float v = acc[pc][j][r] + b2v[r];
        acc[pc][j][r] = v;
        s[r] += v;
        s2[r] += v * v;
      }
#pragma unroll
  for (int off = 1; off < 16; off <<= 1)
#pragma unroll
    for (int r = 0; r < 4; ++r) {
      s[r] += __shfl_xor(s[r], off);
      s2[r] += __shfl_xor(s2[r], off);
    }
  if (cc == 0) {
#pragma unroll
    for (int r = 0; r < 4; ++r) {
      atomicAdd(&chS[wm * 16 + cr + r][0], s[r]);
      atomicAdd(&chS[wm * 16 + cr + r][1], s2[r]);
    }
  }
  __syncthreads();
  if (tid < 8) {
    const int g = tid;
    float ts = 0.f, t2 = 0.f;
#pragma unroll
    for (int c = 0; c < 4; ++c) { ts += chS[g * 4 + c][0]; t2 += chS[g * 4 + c][1]; }
    const float mu = ts * (1.f / 4096.f);
    const float var = t2 * (1.f / 4096.f) - mu * mu;
    gS[g][0] = mu;
    gS[g][1] = rsqrtf(var + 1e-5f);
  }
  __syncthreads();

  // normalize + affine + residual, write out (fp32)
#pragma unroll
  for (int r = 0; r < 4; ++r) {
    const int chl = wm * 16 + cr + r;
    const int ch = ch0 + chl;
    const float mu = gS[chl >> 2][0], rstd = gS[chl >> 2][1];
    const float sc = rstd * gwv[r], sh = gbv[r];
    float* op = out + ((long)n * 512 + ch) * 1024;
    const __hip_bfloat16* xr = Xc + ((long)n * 512 + ch) * 1024;
#pragma unroll
    for (int pc = 0; pc < 4; ++pc)
#pragma unroll
      for (int j = 0; j < 4; ++j) {
        const int px = pc * 256 + wpx * 64 + j * 16 + cc;
        op[px] = (acc[pc][j][r] - mu) * sc + sh + __bfloat162float(xr[px]);
      }
  }
}

extern "C" void kernel_launch(void* const* d_in, const int* in_sizes, int n_in,
                              void* d_out, int out_size, void* d_ws, size_t ws_size,
                              hipStream_t stream) {
  const float* X  = (const float*)d_in[0];
  const float* Wq = (const float*)d_in[1];
  const float* bq = (const float*)d_in[2];
  const float* Wk = (const float*)d_in[3];
  const float* bk = (const float*)d_in[4];
  const float* Wv = (const float*)d_in[5];
  const float* bv = (const float*)d_in[6];
  const float* Wo = (const float*)d_in[7];
  const float* bo = (const float*)d_in[8];
  const float* gw = (const float*)d_in[9];
  const float* gb = (const float*)d_in[10];
  float* out = (float*)d_out;

  char* ws = (char*)d_ws;
  __hip_bfloat16* XT  = (__hip_bfloat16*)(ws + 0);          // 16 MiB [16384][512]
  __hip_bfloat16* KV  = (__hip_bfloat16*)(ws + 16777216);   // 32 MiB [1024][16384]
  __hip_bfloat16* WPP = (__hip_bfloat16*)(ws + 58720256);   // 8 MiB  W'' [16][512][512]
  __hip_bfloat16* Mt  = (__hip_bfloat16*)(ws + 67108864);   // 1 MiB  [16][8][64][64]
  __hip_bfloat16* WA  = (__hip_bfloat16*)(ws + 68157440);   // 1 MiB  [Wq;Wv]
  __hip_bfloat16* WkT = (__hip_bfloat16*)(ws + 69206016);   // 0.5 MiB
  __hip_bfloat16* WOb = (__hip_bfloat16*)(ws + 69730304);   // 0.5 MiB
  float*          bKV = (float*)(ws + 70254592);            // [1024]
  float*          b2  = (float*)(ws + 70258688);            // [16][512] fp32
  __hip_bfloat16* Xc  = (__hip_bfloat16*)(ws + 75497472);   // 16 MiB [16][512][1024] bf16

  // 1. X -> XT (bf16 [n][p][c]) + Xc (bf16 [n][c][p]) + weight casts
  prep<<<dim3(16, 8, 17), 256, 0, stream>>>(X, XT, Xc, Wq, Wv, Wk, Wo, bq, bv,
                                            WA, WkT, WOb, bKV);
  // 2. KV[1024][16384] = [Wq;Wv] * XT^T + [bq;bv]  (XCD-contiguous swizzle)
  gemm_nt<__hip_bfloat16, true, 1><<<1024, 256, 0, stream>>>(
      WA, 0, XT, 0, KV, 0, 512, 16384, bKV, 0);
  // 3. Mt[n,h] = (V_h K_h^T)^T, bf16
  gemm_vkT<<<128, 512, 0, stream>>>(KV + (long)512 * 16384, KV, Mt);
  // 4. W'' = (Wo * blockdiag(M)) * Wk, b2 = W'*bk + bo  (fused chain)
  wchain<<<dim3(4, 4, 16), 256, 0, stream>>>(WOb, WkT, Mt, bk, bo, WPP, b2);
  // 5. fused Y-GEMM + GroupNorm + affine + residual -> out
  ygn<<<256, 512, 0, stream>>>(WPP, XT, b2, Xc, gw, gb, out);
}

// Round 14
// 117.131 us; speedup vs baseline: 1.2598x; 1.0150x over previous
//
#include <hip/hip_runtime.h>
#include <hip/hip_bf16.h>

typedef __attribute__((ext_vector_type(8))) short s8v;
typedef __attribute__((ext_vector_type(4))) short s4v;
typedef __attribute__((ext_vector_type(4))) float f32x4;

#define MFMA_BF16 __builtin_amdgcn_mfma_f32_16x16x32_bf16

__device__ inline void gload_lds16(const __hip_bfloat16* g, __hip_bfloat16* l) {
  __builtin_amdgcn_global_load_lds(
      (const __attribute__((address_space(1))) void*)g,
      (__attribute__((address_space(3))) void*)l, 16, 0, 0);
}

__device__ inline short f2bs(float x) {
  __hip_bfloat16 b = __float2bfloat16(x);
  return *reinterpret_cast<short*>(&b);
}

__device__ inline void storeC(float* p, float v) { *p = v; }
__device__ inline void storeC(__hip_bfloat16* p, float v) { *p = __float2bfloat16(v); }

// ---- prep: (z<16) X[n][c][p] fp32 -> XT[n][p][c] bf16 + Xc[n][c][p] bf16
//      (z==16) weight casts
__global__ __launch_bounds__(256) void prep(const float* __restrict__ X,
                                            __hip_bfloat16* __restrict__ XT,
                                            __hip_bfloat16* __restrict__ Xc,
                                            const float* __restrict__ Wq,
                                            const float* __restrict__ Wv,
                                            const float* __restrict__ Wk,
                                            const float* __restrict__ Wo,
                                            const float* __restrict__ bq,
                                            const float* __restrict__ bv,
                                            __hip_bfloat16* __restrict__ WA,
                                            __hip_bfloat16* __restrict__ WkT,
                                            __hip_bfloat16* __restrict__ WOb,
                                            float* __restrict__ biasKV) {
  const int tid = threadIdx.x;
  if (blockIdx.z == 16) {  // weight casts: 128 blocks x 8 iters x 256 threads
    const int blk = blockIdx.y * 16 + blockIdx.x;
#pragma unroll
    for (int t = 0; t < 8; ++t) {
      const int i = (blk * 8 + t) * 256 + tid;  // < 262144
      WA[i] = __float2bfloat16(Wq[i]);
      WA[262144 + i] = __float2bfloat16(Wv[i]);
      WOb[i] = __float2bfloat16(Wo[i]);
      WkT[i] = __float2bfloat16(Wk[(i & 511) * 512 + (i >> 9)]);
      if (i < 512) { biasKV[i] = bq[i]; biasKV[512 + i] = bv[i]; }
    }
    return;
  }
  __shared__ float tl[64][65];
  const int n = blockIdx.z;
  const int c0 = blockIdx.y * 64, p0 = blockIdx.x * 64;
  const int lr = tid >> 4, lc4 = (tid & 15) * 4;
  const float* Xp = X + ((long)n * 512 + c0) * 1024 + p0;
  __hip_bfloat16* Xcp = Xc + ((long)n * 512 + c0) * 1024 + p0;
#pragma unroll
  for (int i = 0; i < 4; ++i) {
    const int ch = i * 16 + lr;
    const float4 v = *(const float4*)&Xp[(long)ch * 1024 + lc4];
    tl[ch][lc4 + 0] = v.x; tl[ch][lc4 + 1] = v.y;
    tl[ch][lc4 + 2] = v.z; tl[ch][lc4 + 3] = v.w;
    s4v xo;
    xo[0] = f2bs(v.x); xo[1] = f2bs(v.y); xo[2] = f2bs(v.z); xo[3] = f2bs(v.w);
    *(s4v*)&Xcp[(long)ch * 1024 + lc4] = xo;  // straight bf16 copy for residual
  }
  __syncthreads();
  __hip_bfloat16* XTp = XT + ((long)n * 1024 + p0) * 512 + c0;
#pragma unroll
  for (int i = 0; i < 4; ++i) {
    const int px = i * 16 + lr;
    s4v o;
#pragma unroll
    for (int e = 0; e < 4; ++e) o[e] = f2bs(tl[lc4 + e][px]);
    *(s4v*)&XTp[(long)px * 512 + lc4] = o;
  }
}

// ---------------- NT GEMM: C[m][n] = sum_k A[m][k]*B[n][k] (+row bias) -----
// 128x128 tile, 4 waves (2x2), BK=64, global_load_lds staging (m97 structure)
template <typename OutT, bool BROW>
__global__ __launch_bounds__(256) void gemm_nt(
    const __hip_bfloat16* __restrict__ A, long strideA,
    const __hip_bfloat16* __restrict__ B, long strideB,
    OutT* __restrict__ C, long strideC, int K, int ldc,
    const float* __restrict__ brow, long strideBrow) {
  A += blockIdx.z * strideA;
  B += blockIdx.z * strideB;
  C += blockIdx.z * strideC;
  const int m0 = blockIdx.y * 128;
  const int n0 = blockIdx.x * 128;
  const int tid = threadIdx.x;
  const int wid = tid >> 6, lane = tid & 63;
  const int wm = wid >> 1, wn = wid & 1;

  __shared__ __hip_bfloat16 As[128 * 64];
  __shared__ __hip_bfloat16 Bs[128 * 64];

  f32x4 acc[4][4] = {};

  const __hip_bfloat16* gA0 = A + (long)(m0 + wid * 32 + (lane >> 3)) * K + (lane & 7) * 8;
  const __hip_bfloat16* gB0 = B + (long)(n0 + wid * 32 + (lane >> 3)) * K + (lane & 7) * 8;

  for (int k0 = 0; k0 < K; k0 += 64) {
#pragma unroll
    for (int t = 0; t < 4; ++t) {
      gload_lds16(gA0 + (long)t * 8 * K + k0, &As[(wid * 32 + t * 8) * 64]);
      gload_lds16(gB0 + (long)t * 8 * K + k0, &Bs[(wid * 32 + t * 8) * 64]);
    }
    __syncthreads();
#pragma unroll
    for (int ks = 0; ks < 2; ++ks) {
      const int koff = ks * 32 + (lane >> 4) * 8;
      s8v a[4], b[4];
#pragma unroll
      for (int i = 0; i < 4; ++i)
        a[i] = *(const s8v*)&As[(wm * 64 + i * 16 + (lane & 15)) * 64 + koff];
#pragma unroll
      for (int j = 0; j < 4; ++j)
        b[j] = *(const s8v*)&Bs[(wn * 64 + j * 16 + (lane & 15)) * 64 + koff];
#pragma unroll
      for (int i = 0; i < 4; ++i)
#pragma unroll
        for (int j = 0; j < 4; ++j)
          acc[i][j] = MFMA_BF16(a[i], b[j], acc[i][j], 0, 0, 0);
    }
    __syncthreads();
  }

  const int cr = (lane >> 4) * 4;
  const int cc = lane & 15;
#pragma unroll
  for (int i = 0; i < 4; ++i) {
#pragma unroll
    for (int r = 0; r < 4; ++r) {
      const int gm = m0 + wm * 64 + i * 16 + cr + r;
      const float rb = BROW ? brow[blockIdx.z * strideBrow + gm] : 0.f;
#pragma unroll
      for (int j = 0; j < 4; ++j) {
        const int gn = n0 + wn * 64 + j * 16 + cc;
        storeC(&C[(long)gm * ldc + gn], acc[i][j][r] + rb);
      }
    }
  }
}

// -------- Mt[n,h][j][i] = (V_h K_h^T)[i][j] bf16 (K-reduce 1024, 8 waves) --
__global__ __launch_bounds__(512) void gemm_vkT(const __hip_bfloat16* __restrict__ V,
                                                const __hip_bfloat16* __restrict__ Kk,
                                                __hip_bfloat16* __restrict__ Mt) {
  const int n = blockIdx.x >> 3, h = blockIdx.x & 7;
  const int tid = threadIdx.x, wid = tid >> 6, lane = tid & 63;
  f32x4 acc[4][4] = {};
  const long colbase = (long)n * 1024 + wid * 128 + (lane >> 4) * 8;
  const __hip_bfloat16* Vb = V + (long)(h * 64 + (lane & 15)) * 16384 + colbase;
  const __hip_bfloat16* Kb = Kk + (long)(h * 64 + (lane & 15)) * 16384 + colbase;
#pragma unroll
  for (int kk = 0; kk < 128; kk += 32) {
    s8v a[4], b[4];
#pragma unroll
    for (int i = 0; i < 4; ++i) a[i] = *(const s8v*)(Vb + (long)i * 16 * 16384 + kk);
#pragma unroll
    for (int j = 0; j < 4; ++j) b[j] = *(const s8v*)(Kb + (long)j * 16 * 16384 + kk);
#pragma unroll
    for (int i = 0; i < 4; ++i)
#pragma unroll
      for (int j = 0; j < 4; ++j) acc[i][j] = MFMA_BF16(a[i], b[j], acc[i][j], 0, 0, 0);
  }
  __shared__ float part[4][4096];
  const int cr = (lane >> 4) * 4, cc = lane & 15;
  if (wid < 4) {
#pragma unroll
    for (int i = 0; i < 4; ++i)
#pragma unroll
      for (int r = 0; r < 4; ++r)
#pragma unroll
        for (int j = 0; j < 4; ++j)
          part[wid][(i * 16 + cr + r) * 64 + j * 16 + cc] = acc[i][j][r];
  }
  __syncthreads();
  if (wid >= 4) {
#pragma unroll
    for (int i = 0; i < 4; ++i)
#pragma unroll
      for (int r = 0; r < 4; ++r)
#pragma unroll
        for (int j = 0; j < 4; ++j)
          part[wid - 4][(i * 16 + cr + r) * 64 + j * 16 + cc] += acc[i][j][r];
  }
  __syncthreads();
  __hip_bfloat16* outp = Mt + ((long)n * 8 + h) * 4096;
  for (int e = tid; e < 4096; e += 512) {
    const float sum = part[0][e] + part[1][e] + part[2][e] + part[3][e];
    outp[(e & 63) * 64 + (e >> 6)] = __float2bfloat16(sum);  // Mt[j][i]=M[i][j]
  }
}

// ---- wchain: W''[n] = (Wo * blockdiag(M[n])) * Wk,  b2[n] = W'*bk + bo ----
__global__ __launch_bounds__(256) void wchain(const __hip_bfloat16* __restrict__ WOb,
                                              const __hip_bfloat16* __restrict__ WkT,
                                              const __hip_bfloat16* __restrict__ Mt,
                                              const float* __restrict__ bk,
                                              const float* __restrict__ bo,
                                              __hip_bfloat16* __restrict__ WPP,
                                              float* __restrict__ b2out) {
  const int c0 = blockIdx.x * 128, o0 = blockIdx.y * 128, n = blockIdx.z;
  const int tid = threadIdx.x, wid = tid >> 6, lane = tid & 63;
  const int wm = wid >> 1, wn = wid & 1;
  const int cr = (lane >> 4) * 4, cc = lane & 15;

  __shared__ __hip_bfloat16 WoS[128 * 64];
  __shared__ __hip_bfloat16 WkS[128 * 64];
  __shared__ __hip_bfloat16 MtS[64 * 64];
  __shared__ __hip_bfloat16 W1S[128 * 64];
  __shared__ float bkS[512];

  if (tid < 128) *(float4*)&bkS[tid * 4] = *(const float4*)&bk[tid * 4];

  f32x4 acc2[4][4] = {};
  float bacc = 0.f;
  const int r8 = lane >> 3, b8 = (lane & 7) * 8;

  for (int h = 0; h < 8; ++h) {
#pragma unroll
    for (int t = 0; t < 4; ++t) {
      const int row = wid * 32 + t * 8;
      gload_lds16(WOb + (long)(o0 + row + r8) * 512 + h * 64 + b8, &WoS[row * 64]);
      gload_lds16(WkT + (long)(c0 + row + r8) * 512 + h * 64 + b8, &WkS[row * 64]);
    }
    {
      const __hip_bfloat16* mg = Mt + ((long)n * 8 + h) * 4096;
      gload_lds16(mg + wid * 512 + lane * 8, &MtS[wid * 512]);
      gload_lds16(mg + 2048 + wid * 512 + lane * 8, &MtS[2048 + wid * 512]);
    }
    __syncthreads();

    f32x4 acc1[2][4] = {};
#pragma unroll
    for (int ks = 0; ks < 2; ++ks) {
      const int ko = ks * 32 + (lane >> 4) * 8;
      s8v aj[2], bw[4];
#pragma unroll
      for (int i = 0; i < 2; ++i)
        aj[i] = *(const s8v*)&MtS[(wn * 32 + i * 16 + cc) * 64 + ko];
#pragma unroll
      for (int t = 0; t < 4; ++t)
        bw[t] = *(const s8v*)&WoS[(wm * 64 + t * 16 + cc) * 64 + ko];
#pragma unroll
      for (int i = 0; i < 2; ++i)
#pragma unroll
        for (int t = 0; t < 4; ++t)
          acc1[i][t] = MFMA_BF16(aj[i], bw[t], acc1[i][t], 0, 0, 0);
    }
#pragma unroll
    for (int i = 0; i < 2; ++i)
#pragma unroll
      for (int t = 0; t < 4; ++t) {
        const int o = wm * 64 + t * 16 + cc;
        const int jb = wn * 32 + i * 16 + cr;
        s4v p;
#pragma unroll
        for (int r = 0; r < 4; ++r) p[r] = f2bs(acc1[i][t][r]);
        *(s4v*)((char*)W1S + ((o * 128 + jb * 2) ^ ((o & 7) << 4))) = p;
      }
    __syncthreads();

#pragma unroll
    for (int ks = 0; ks < 2; ++ks) {
      const int ko = ks * 32 + (lane >> 4) * 8;
      s8v a2[4], bw[4];
#pragma unroll
      for (int i = 0; i < 4; ++i) {
        const int o = wm * 64 + i * 16 + cc;
        a2[i] = *(const s8v*)((char*)W1S + ((o * 128 + ko * 2) ^ ((o & 7) << 4)));
      }
#pragma unroll
      for (int t = 0; t < 4; ++t)
        bw[t] = *(const s8v*)&WkS[(wn * 64 + t * 16 + cc) * 64 + ko];
#pragma unroll
      for (int i = 0; i < 4; ++i)
#pragma unroll
        for (int t = 0; t < 4; ++t)
          acc2[i][t] = MFMA_BF16(a2[i], bw[t], acc2[i][t], 0, 0, 0);
    }

    if (c0 == 0) {
      const int o = tid >> 1, half = tid & 1;
      float s = 0.f;
#pragma unroll
      for (int q = 0; q < 4; ++q) {
        const int jb = half * 64 + q * 16;
        const s8v w = *(const s8v*)((char*)W1S + ((o * 128 + jb) ^ ((o & 7) << 4)));
        const __hip_bfloat16* wb = (const __hip_bfloat16*)&w;
#pragma unroll
        for (int e = 0; e < 8; ++e)
          s += __bfloat162float(wb[e]) * bkS[h * 64 + half * 32 + q * 8 + e];
      }
      bacc += s;
    }
    __syncthreads();
  }

#pragma unroll
  for (int i = 0; i < 4; ++i)
#pragma unroll
    for (int r = 0; r < 4; ++r)
#pragma unroll
      for (int t = 0; t < 4; ++t)
        WPP[((long)n * 512 + o0 + wm * 64 + i * 16 + cr + r) * 512 +
            c0 + wn * 64 + t * 16 + cc] = __float2bfloat16(acc2[i][t][r]);
  if (c0 == 0) {
    const float tot = bacc + __shfl_xor(bacc, 1);
    if ((tid & 1) == 0) {
      const int o = tid >> 1;
      b2out[n * 512 + o0 + o] = tot + bo[o0 + o];
    }
  }
}

// ---- GroupNorm(128 groups of 4ch x 1024px) + affine + Xc (Y, Xc bf16) -----
__global__ __launch_bounds__(256) void gn_res(const __hip_bfloat16* __restrict__ Y,
                                              const __hip_bfloat16* __restrict__ Xc,
                                              const float* __restrict__ gw,
                                              const float* __restrict__ gb,
                                              float* __restrict__ out) {
  const int n = blockIdx.x >> 7, g = blockIdx.x & 127;
  const long base = ((long)n * 512 + g * 4) * 1024;
  const int tid = threadIdx.x;
  float v[16];
  float s = 0.f, s2 = 0.f;
#pragma unroll
  for (int i = 0; i < 2; ++i) {
    const s8v x = *(const s8v*)&Y[base + ((long)(i * 256 + tid)) * 8];
#pragma unroll
    for (int e = 0; e < 8; ++e) {
      const float f = __bfloat162float(((const __hip_bfloat16*)&x)[e]);
      v[i * 8 + e] = f;
      s += f;
      s2 += f * f;
    }
  }
#pragma unroll
  for (int off = 32; off; off >>= 1) {
    s += __shfl_down(s, off);
    s2 += __shfl_down(s2, off);
  }
  __shared__ float rs[8];
  const int wid = tid >> 6, lane = tid & 63;
  if (lane == 0) { rs[wid] = s; rs[4 + wid] = s2; }
  __syncthreads();
  if (tid == 0) {
    const float ts = rs[0] + rs[1] + rs[2] + rs[3];
    const float t2 = rs[4] + rs[5] + rs[6] + rs[7];
    const float mu = ts * (1.f / 4096.f);
    const float var = t2 * (1.f / 4096.f) - mu * mu;
    rs[0] = mu;
    rs[1] = rsqrtf(var + 1e-5f);
  }
  __syncthreads();
  const float mu = rs[0], rstd = rs[1];
#pragma unroll
  for (int i = 0; i < 2; ++i) {
    const int chunk = i * 256 + tid;
    const long e0 = base + (long)chunk * 8;
    const int c = g * 4 + (chunk >> 7);
    const float sc = rstd * gw[c], sh = gb[c];
    const s8v xv = *(const s8v*)&Xc[e0];
    const __hip_bfloat16* xb = (const __hip_bfloat16*)&xv;
    float4 o0, o1;
    o0.x = (v[i * 8 + 0] - mu) * sc + sh + __bfloat162float(xb[0]);
    o0.y = (v[i * 8 + 1] - mu) * sc + sh + __bfloat162float(xb[1]);
    o0.z = (v[i * 8 + 2] - mu) * sc + sh + __bfloat162float(xb[2]);
    o0.w = (v[i * 8 + 3] - mu) * sc + sh + __bfloat162float(xb[3]);
    o1.x = (v[i * 8 + 4] - mu) * sc + sh + __bfloat162float(xb[4]);
    o1.y = (v[i * 8 + 5] - mu) * sc + sh + __bfloat162float(xb[5]);
    o1.z = (v[i * 8 + 6] - mu) * sc + sh + __bfloat162float(xb[6]);
    o1.w = (v[i * 8 + 7] - mu) * sc + sh + __bfloat162float(xb[7]);
    *(float4*)&out[e0] = o0;
    *(float4*)&out[e0 + 4] = o1;
  }
}

extern "C" void kernel_launch(void* const* d_in, const int* in_sizes, int n_in,
                              void* d_out, int out_size, void* d_ws, size_t ws_size,
                              hipStream_t stream) {
  const float* X  = (const float*)d_in[0];
  const float* Wq = (const float*)d_in[1];
  const float* bq = (const float*)d_in[2];
  const float* Wk = (const float*)d_in[3];
  const float* bk = (const float*)d_in[4];
  const float* Wv = (const float*)d_in[5];
  const float* bv = (const float*)d_in[6];
  const float* Wo = (const float*)d_in[7];
  const float* bo = (const float*)d_in[8];
  const float* gw = (const float*)d_in[9];
  const float* gb = (const float*)d_in[10];
  float* out = (float*)d_out;

  char* ws = (char*)d_ws;
  __hip_bfloat16* XT  = (__hip_bfloat16*)(ws + 0);          // 16 MiB [16384][512]
  __hip_bfloat16* KV  = (__hip_bfloat16*)(ws + 16777216);   // 32 MiB [1024][16384]
  __hip_bfloat16* Y   = (__hip_bfloat16*)(ws + 16777216);   // 16 MiB, overlays KV (dead after vkT)
  __hip_bfloat16* WPP = (__hip_bfloat16*)(ws + 58720256);   // 8 MiB  W'' [16][512][512]
  __hip_bfloat16* Mt  = (__hip_bfloat16*)(ws + 67108864);   // 1 MiB  [16][8][64][64]
  __hip_bfloat16* WA  = (__hip_bfloat16*)(ws + 68157440);   // 1 MiB  [Wq;Wv]
  __hip_bfloat16* WkT = (__hip_bfloat16*)(ws + 69206016);   // 0.5 MiB
  __hip_bfloat16* WOb = (__hip_bfloat16*)(ws + 69730304);   // 0.5 MiB
  float*          bKV = (float*)(ws + 70254592);            // [1024]
  float*          b2  = (float*)(ws + 70258688);            // [16][512] fp32
  __hip_bfloat16* Xc  = (__hip_bfloat16*)(ws + 75497472);   // 16 MiB [16][512][1024] bf16

  // 1. X -> XT (bf16 [n][p][c]) + Xc (bf16 [n][c][p]) + weight casts
  prep<<<dim3(16, 8, 17), 256, 0, stream>>>(X, XT, Xc, Wq, Wv, Wk, Wo, bq, bv,
                                            WA, WkT, WOb, bKV);
  // 2. KV[1024][16384] = [Wq;Wv] * XT^T + [bq;bv]
  gemm_nt<__hip_bfloat16, true><<<dim3(128, 8, 1), 256, 0, stream>>>(
      WA, 0, XT, 0, KV, 0, 512, 16384, bKV, 0);
  // 3. Mt[n,h] = (V_h K_h^T)^T, bf16
  gemm_vkT<<<128, 512, 0, stream>>>(KV + (long)512 * 16384, KV, Mt);
  // 4. W'' = (Wo * blockdiag(M)) * Wk, b2 = W'*bk + bo  (fused chain)
  wchain<<<dim3(4, 4, 16), 256, 0, stream>>>(WOb, WkT, Mt, bk, bo, WPP, b2);
  // 5. Y[n][512][1024] = W''[n] * XT[n]^T + b2[n]   (bf16)
  gemm_nt<__hip_bfloat16, true><<<dim3(8, 4, 16), 256, 0, stream>>>(
      WPP, 262144, XT, 524288, Y, 524288, 512, 1024, b2, 512);
  // 6. GroupNorm + affine + residual (bf16 residual read)
  gn_res<<<2048, 256, 0, stream>>>(Y, Xc, gw, gb, out);
}